// Round 6
// baseline (180.317 us; speedup 1.0000x reference)
//
#include <hip/hip_runtime.h>
#include <cstdint>

#define OUT_S_OFF 33554432ull   // 8*4096*64*16

typedef short s16x8 __attribute__((ext_vector_type(8)));
typedef float f32x4 __attribute__((ext_vector_type(4)));
typedef unsigned int u32x2 __attribute__((ext_vector_type(2)));

// ---------------- compile-time geometric algebra tables ----------------
constexpr int BM_[16]   = {0,1,2,4,8,3,5,9,6,10,12,7,11,13,14,15};
constexpr int IDXm_[16] = {0,1,2,5,3,6,8,11,4,7,9,12,10,13,14,15};
constexpr int G_[16]    = {0,1,1,1,1,2,2,2,2,2,2,3,3,3,3,4};
constexpr int SRC_[16]  = {0,0,2,3,4,2,3,4,8,9,10,8,9,10,14,14};
constexpr int HASP_[16] = {0,1,0,0,0,1,1,1,0,0,0,1,1,1,0,1};
constexpr int A2_[16]   = {0,5,0,0,0,6,6,6,0,0,0,7,7,7,0,8};

constexpr int pcnt_(int x){ int c=0; for(int b=0;b<8;b++) c += (x>>b)&1; return c; }
constexpr int par_(int A,int B){ int sw=0; for(int b=0;b<4;b++) if((B>>b)&1) sw += pcnt_(A>>(b+1)); return (sw&1)?-1:1; }
constexpr int sgnv_(int b){ return par_(BM_[b], 15 & ~BM_[b]); }

struct GTab { int cnt[16]; signed char jj[16][16]; signed char kk[16][16]; signed char ss[16][16]; };

constexpr GTab mk_cayley(){
  GTab t{};
  for(int j=0;j<16;j++) for(int k=0;k<16;k++){
    int A=BM_[j], B=BM_[k];
    if(A & B & 1) continue;
    int i = IDXm_[A^B]; int s = par_(A,B);
    int n = t.cnt[i]; t.jj[i][n]=(signed char)j; t.kk[i][n]=(signed char)k; t.ss[i][n]=(signed char)s; t.cnt[i]=n+1;
  }
  return t;
}
constexpr GTab mk_join(){
  GTab t{};
  for(int j=0;j<16;j++) for(int k=0;k<16;k++){
    int cj = 15 & ~BM_[j], ck = 15 & ~BM_[k];
    if(cj & ck) continue;
    int m  = cj | ck;
    int w  = par_(cj, ck);
    int mp = IDXm_[15 & ~m];
    int s  = sgnv_(j)*sgnv_(k)*w*sgnv_(mp);
    int n = t.cnt[mp]; t.jj[mp][n]=(signed char)j; t.kk[mp][n]=(signed char)k; t.ss[mp][n]=(signed char)s; t.cnt[mp]=n+1;
  }
  return t;
}

__device__ __forceinline__ unsigned short f2bf(float f){
  unsigned u = __float_as_uint(f);
  return (unsigned short)((u + 0x7fffu + ((u>>16)&1u)) >> 16);
}
__device__ __forceinline__ unsigned int pack2(float a, float b){
  return (unsigned int)f2bf(a) | ((unsigned int)f2bf(b) << 16);
}

// ---------------- slab-indexed prepacked weights (B-operand fragments) ----------------
// frag element (lane,j): local-y = lane&15 ; k-in-32 = ((lane>>4)&3)*8 + j
__device__ unsigned short g_WinSlab [4*9*2*2*512]; // [m][d 0..8][s 0..1][h]  (147KB)
__device__ unsigned short g_WinS2   [4*2*2*512];   // [m][s][h]               (16KB)
__device__ unsigned short g_WoutSlab[9*2*4*512];   // [d][s][nt]              (72KB)
__device__ unsigned short g_WoutS2  [4*4*512];     // [ss][nt]                (16KB)
__device__ unsigned short g_WsB     [6*4*512];     // [s 0..5][nt]            (24KB)

__global__ __launch_bounds__(256) void prepack(
    const float* wL, const float* wR, const float* wJL, const float* wJR, const float* wO,
    const float* s2L, const float* s2R, const float* s2JL, const float* s2JR,
    const float* s2O, const float* mv2s, const float* s2s)
{
  int idx = blockIdx.x*256 + threadIdx.x;
  if (idx < 73728) {                         // g_WinSlab
    int j=idx&7, l=(idx>>3)&63, h=(idx>>9)&1, s=(idx>>10)&1;
    int md=idx>>11; int d=md%9, m=md/9;
    int y=h*16+(l&15), k=s*32+((l>>4)&3)*8+j;
    const float* w = (m==0)?wL:(m==1)?wR:(m==2)?wJL:wJR;
    g_WinSlab[idx] = f2bf(w[(y*64+k)*9 + d]);
  } else if (idx < 81920) {                  // g_WinS2
    int t2=idx-73728;
    int j=t2&7, l=(t2>>3)&63, h=(t2>>9)&1, s=(t2>>10)&1, m=t2>>11;
    int y=h*16+(l&15), k=s*32+((l>>4)&3)*8+j;
    const float* s2 = (m==0)?s2L:(m==1)?s2R:(m==2)?s2JL:s2JR;
    g_WinS2[t2] = f2bf(s2[y*64+k]);
  } else if (idx < 118784) {                 // g_WoutSlab
    int t3=idx-81920;
    int j=t3&7, l=(t3>>3)&63, nt=(t3>>9)&3, s=(t3>>11)&1, d=t3>>12;
    int y=nt*16+(l&15), k=s*32+((l>>4)&3)*8+j;
    g_WoutSlab[t3] = f2bf(wO[(y*64+k)*9 + d]);
  } else if (idx < 126976) {                 // g_WoutS2
    int t4=idx-118784;
    int j=t4&7, l=(t4>>3)&63, nt=(t4>>9)&3, ss=t4>>11;
    int y=nt*16+(l&15), kk=((l>>4)&3)*8+j;
    g_WoutS2[t4] = f2bf(s2O[y*128 + ss*32 + kk]);
  } else if (idx < 139264) {                 // g_WsB
    int t5=idx-126976;
    int j=t5&7, l=(t5>>3)&63, nt=(t5>>9)&3, s=t5>>11;
    int y=nt*16+(l&15), kk=((l>>4)&3)*8+j;
    float v = (s<2) ? mv2s[y*64 + s*32 + kk] : s2s[y*128 + (s-2)*32 + kk];
    g_WsB[t5] = f2bf(v);
  }
}

// ---------------- fused main kernel ----------------
// 512 threads = 8 waves, 32 tokens/block, single 64KB mv buffer (restaged).
// P1/P2 roles: (g = w>>2, h = (w>>1)&1, sb = w&1) ; P3 roles: (nt = w&3, sb = w>>2)
__global__ __launch_bounds__(512, 4) void fused(
    const float* __restrict__ mv1, const float* __restrict__ mv2,
    const float* __restrict__ sc1, const float* __restrict__ sc2,
    const float* __restrict__ refmv, const float* __restrict__ bias,
    float* __restrict__ out)
{
  __shared__ unsigned int s_mv[16384];  // [(i*32+t)*32 + dw], 64KB; mv1 -> mv2 -> hidden
  __shared__ unsigned int s_sc[2048];   // [t*64 + dw], 8KB (s_cat bf16, swizzled)
  __shared__ float s_ref[32];

  const int tid  = threadIdx.x;
  const int lane = tid & 63, w = tid >> 6;
  const int tr   = lane & 15, u = lane >> 4;
  const int g    = w >> 2, h = (w >> 1) & 1, sb = w & 1;
  const size_t tok0 = (size_t)blockIdx.x * 32;

  auto stage_load = [&](const float* __restrict__ src, int it, float4* Fr){
    int flat = tid + it*512;            // 0..1023
    int x2 = flat & 31, t = flat >> 5;  // x2: ch-pair group, t: token
    const float* b0 = src + (tok0+t)*1024 + x2*32;
    #pragma unroll
    for (int q=0;q<4;q++){
      Fr[q]   = *(const float4*)(b0 + q*4);
      Fr[4+q] = *(const float4*)(b0 + 16 + q*4);
    }
  };
  auto stage_write = [&](int it, const float4* Fr){
    int flat = tid + it*512;
    int x2 = flat & 31, t = flat >> 5;
    unsigned int* dst = &s_mv[t*32 + (x2 ^ ((t&7)<<2))];
    #pragma unroll
    for (int q=0;q<4;q++){
      #pragma unroll
      for (int e=0;e<4;e++){
        int i = q*4 + e;
        dst[i*1024] = pack2(((const float*)&Fr[q])[e], ((const float*)&Fr[4+q])[e]);
      }
    }
  };

  auto afragS = [&](int comp, int sh, int sbl)->s16x8 {   // A-frag at subtile sbl
    const unsigned short* p = (const unsigned short*)s_mv;
    int trow = sbl*16 + tr;
    return *(const s16x8*)&p[(comp*32 + trow)*64 + (((sh*4 + u) ^ (tr&7)) << 3)];
  };
  auto scfragS = [&](int ss, int sbl)->s16x8 {
    const unsigned short* p = (const unsigned short*)s_sc;
    int trow = sbl*16 + tr;
    return *(const s16x8*)&p[trow*128 + (((ss*4 + u) ^ (tr&7)) << 3)];
  };
  auto slabIn = [&](int m,int d,int s)->s16x8 {
    return *(const s16x8*)&g_WinSlab[((((m*9+d)*2+s)*2+h)*512) + lane*8];
  };
  auto s2In = [&](int m,int s)->s16x8 {
    return *(const s16x8*)&g_WinS2[(((m*2+s)*2+h)*512) + lane*8];
  };
  auto slabOut = [&](int d,int s,int nt)->s16x8 {
    return *(const s16x8*)&g_WoutSlab[(((d*2+s)*4+nt)*512) + lane*8];
  };
  auto s2Out = [&](int ss,int nt)->s16x8 {
    return *(const s16x8*)&g_WoutS2[((ss*4+nt)*512) + lane*8];
  };
  auto bfragS = [&](int s,int nt)->s16x8 {
    return *(const s16x8*)&g_WsB[((s*4+nt)*512) + lane*8];
  };

  // ---- P0: stage mv1 (both halves issued together) + scalars + ref ----
  {
    float4 F0[8], F1[8];
    stage_load(mv1, 0, F0);
    stage_load(mv1, 1, F1);
    #pragma unroll
    for (int it=0; it<4; ++it){
      int flat = tid + it*512;           // 0..2047
      int cp = flat & 63, t = flat >> 6;
      float a, b;
      if (cp < 32){ const float* p = sc1 + (tok0+t)*64 + cp*2;      a=p[0]; b=p[1]; }
      else        { const float* p = sc2 + (tok0+t)*64 + (cp-32)*2; a=p[0]; b=p[1]; }
      s_sc[t*64 + (cp ^ ((t&7)<<2))] = pack2(a,b);
    }
    if (tid < 32) s_ref[tid] = refmv[(tok0+tid)*16 + 15];
    stage_write(0, F0);
    stage_write(1, F1);
  }
  __syncthreads();

  // ---- P1a: A-side maps from mv1 (gp: L ; join: JL); sc1 folded; pack to bf16 ----
  u32x2 accAp[16], accBp[16];
  const int mA = (g==0) ? 0 : 2;
  const int mB = (g==0) ? 1 : 3;
  #pragma unroll
  for (int i=0;i<16;i++){
    f32x4 a = (f32x4)0.f;
    a = __builtin_amdgcn_mfma_f32_16x16x32_bf16(afragS(i,0,sb), slabIn(mA,G_[i],0), a,0,0,0);
    a = __builtin_amdgcn_mfma_f32_16x16x32_bf16(afragS(i,1,sb), slabIn(mA,G_[i],1), a,0,0,0);
    if (HASP_[i]){
      a = __builtin_amdgcn_mfma_f32_16x16x32_bf16(afragS(SRC_[i],0,sb), slabIn(mA,A2_[i],0), a,0,0,0);
      a = __builtin_amdgcn_mfma_f32_16x16x32_bf16(afragS(SRC_[i],1,sb), slabIn(mA,A2_[i],1), a,0,0,0);
    } else if (i==0){
      a = __builtin_amdgcn_mfma_f32_16x16x32_bf16(scfragS(0,sb), s2In(mA,0), a,0,0,0);
      a = __builtin_amdgcn_mfma_f32_16x16x32_bf16(scfragS(1,sb), s2In(mA,1), a,0,0,0);
    }
    accAp[i].x = pack2(a[0], a[1]);
    accAp[i].y = pack2(a[2], a[3]);
  }
  __syncthreads();

  // ---- P0b: restage with mv2 (two low-register-pressure half passes) ----
  {
    float4 F[8];
    stage_load(mv2, 0, F);
    stage_write(0, F);
    stage_load(mv2, 1, F);
    stage_write(1, F);
  }
  __syncthreads();

  // ---- P1c: B-side maps from mv2 (gp: R ; join: JR); sc2 folded ----
  #pragma unroll
  for (int i=0;i<16;i++){
    f32x4 b = (f32x4)0.f;
    b = __builtin_amdgcn_mfma_f32_16x16x32_bf16(afragS(i,0,sb), slabIn(mB,G_[i],0), b,0,0,0);
    b = __builtin_amdgcn_mfma_f32_16x16x32_bf16(afragS(i,1,sb), slabIn(mB,G_[i],1), b,0,0,0);
    if (HASP_[i]){
      b = __builtin_amdgcn_mfma_f32_16x16x32_bf16(afragS(SRC_[i],0,sb), slabIn(mB,A2_[i],0), b,0,0,0);
      b = __builtin_amdgcn_mfma_f32_16x16x32_bf16(afragS(SRC_[i],1,sb), slabIn(mB,A2_[i],1), b,0,0,0);
    } else if (i==0){
      b = __builtin_amdgcn_mfma_f32_16x16x32_bf16(scfragS(2,sb), s2In(mB,0), b,0,0,0);
      b = __builtin_amdgcn_mfma_f32_16x16x32_bf16(scfragS(3,sb), s2In(mB,1), b,0,0,0);
    }
    accBp[i].x = pack2(b[0], b[1]);
    accBp[i].y = pack2(b[2], b[3]);
  }
  __syncthreads();   // all reads of s_mv done before hidden overwrite

  // ---- P2: Cayley GP / join from packed-bf16 regs; write hidden (aliases s_mv) ----
  {
    unsigned short* hidp = (unsigned short*)s_mv;
    const int c = g*32 + h*16 + tr;
    if (g == 0){
      constexpr GTab CAY = mk_cayley();
      #pragma unroll
      for (int r=0;r<4;r++){
        const int t = sb*16 + u*4 + r;
        float L[16], R[16];
        #pragma unroll
        for (int j2=0;j2<16;j2++){
          unsigned wa = (r&2) ? accAp[j2].y : accAp[j2].x;
          unsigned wb = (r&2) ? accBp[j2].y : accBp[j2].x;
          L[j2] = __uint_as_float((r&1) ? (wa & 0xffff0000u) : (wa << 16));
          R[j2] = __uint_as_float((r&1) ? (wb & 0xffff0000u) : (wb << 16));
        }
        #pragma unroll
        for (int i=0;i<16;i++){
          float a = 0.f;
          #pragma unroll
          for (int e=0;e<CAY.cnt[i];e++){
            float p = L[(int)CAY.jj[i][e]] * R[(int)CAY.kk[i][e]];
            a = (CAY.ss[i][e] > 0) ? (a + p) : (a - p);
          }
          hidp[(i*32 + t)*64 + (c ^ ((t&7)<<3))] = f2bf(a);
        }
      }
    } else {
      constexpr GTab JNT = mk_join();
      #pragma unroll
      for (int r=0;r<4;r++){
        const int t = sb*16 + u*4 + r;
        float rv = s_ref[t];
        float L[16], R[16];
        #pragma unroll
        for (int j2=0;j2<16;j2++){
          unsigned wa = (r&2) ? accAp[j2].y : accAp[j2].x;
          unsigned wb = (r&2) ? accBp[j2].y : accBp[j2].x;
          L[j2] = __uint_as_float((r&1) ? (wa & 0xffff0000u) : (wa << 16));
          R[j2] = __uint_as_float((r&1) ? (wb & 0xffff0000u) : (wb << 16));
        }
        #pragma unroll
        for (int i=0;i<16;i++){
          float a = 0.f;
          #pragma unroll
          for (int e=0;e<JNT.cnt[i];e++){
            float p = L[(int)JNT.jj[i][e]] * R[(int)JNT.kk[i][e]];
            a = (JNT.ss[i][e] > 0) ? (a + p) : (a - p);
          }
          hidp[(i*32 + t)*64 + (c ^ ((t&7)<<3))] = f2bf(a * rv);
        }
      }
    }
  }
  __syncthreads();

  // ---- P3: output equi-linear + scalar head via MFMA; wave = (nt, subtile) ----
  {
    const int nt = w & 3, sb3 = w >> 2;
    f32x4 accO[16]; f32x4 accS = (f32x4)0.f;
    #pragma unroll
    for (int i=0;i<16;i++) accO[i] = (f32x4)0.f;

    s16x8 h00 = afragS(0,0,sb3), h01 = afragS(0,1,sb3);

    #pragma unroll
    for (int i=0;i<16;i++){
      s16x8 a0 = (i==0) ? h00 : afragS(i,0,sb3);
      s16x8 a1 = (i==0) ? h01 : afragS(i,1,sb3);
      accO[i] = __builtin_amdgcn_mfma_f32_16x16x32_bf16(a0, slabOut(G_[i],0,nt), accO[i],0,0,0);
      accO[i] = __builtin_amdgcn_mfma_f32_16x16x32_bf16(a1, slabOut(G_[i],1,nt), accO[i],0,0,0);
      if (HASP_[i]){
        accO[i] = __builtin_amdgcn_mfma_f32_16x16x32_bf16(afragS(SRC_[i],0,sb3), slabOut(A2_[i],0,nt), accO[i],0,0,0);
        accO[i] = __builtin_amdgcn_mfma_f32_16x16x32_bf16(afragS(SRC_[i],1,sb3), slabOut(A2_[i],1,nt), accO[i],0,0,0);
      } else if (i==0){
        #pragma unroll
        for (int ss=0;ss<4;ss++)
          accO[0] = __builtin_amdgcn_mfma_f32_16x16x32_bf16(scfragS(ss,sb3), s2Out(ss,nt), accO[0],0,0,0);
      }
    }
    accS = __builtin_amdgcn_mfma_f32_16x16x32_bf16(h00, bfragS(0,nt), accS,0,0,0);
    accS = __builtin_amdgcn_mfma_f32_16x16x32_bf16(h01, bfragS(1,nt), accS,0,0,0);
    #pragma unroll
    for (int ss=0;ss<4;ss++)
      accS = __builtin_amdgcn_mfma_f32_16x16x32_bf16(scfragS(ss,sb3), bfragS(2+ss,nt), accS,0,0,0);

    const int y = nt*16 + tr;
    const float bv = bias[y];
    #pragma unroll
    for (int r=0;r<4;r++){
      const int t = sb3*16 + u*4 + r;
      out[OUT_S_OFF + (tok0+t)*64 + y] = accS[r] + bv;
      float* ob = out + (tok0+t)*1024 + y*16;
      #pragma unroll
      for (int iq=0;iq<4;iq++){
        f32x4 v = { accO[iq*4+0][r], accO[iq*4+1][r], accO[iq*4+2][r], accO[iq*4+3][r] };
        *(f32x4*)(ob + iq*4) = v;
      }
    }
  }
}

extern "C" void kernel_launch(void* const* d_in, const int* in_sizes, int n_in,
                              void* d_out, int out_size, void* d_ws, size_t ws_size,
                              hipStream_t stream) {
  const float* mv1   = (const float*)d_in[0];
  const float* mv2   = (const float*)d_in[1];
  const float* sc1   = (const float*)d_in[2];
  const float* sc2   = (const float*)d_in[3];
  const float* refmv = (const float*)d_in[4];
  const float* wL    = (const float*)d_in[5];
  const float* s2L   = (const float*)d_in[6];
  const float* wR    = (const float*)d_in[7];
  const float* s2R   = (const float*)d_in[8];
  const float* wJL   = (const float*)d_in[9];
  const float* s2JL  = (const float*)d_in[10];
  const float* wJR   = (const float*)d_in[11];
  const float* s2JR  = (const float*)d_in[12];
  const float* wO    = (const float*)d_in[13];
  const float* s2O   = (const float*)d_in[14];
  const float* mv2s  = (const float*)d_in[15];
  const float* s2s   = (const float*)d_in[16];
  const float* bias  = (const float*)d_in[17];
  float* out = (float*)d_out;

  prepack<<<544, 256, 0, stream>>>(wL,wR,wJL,wJR,wO, s2L,s2R,s2JL,s2JR, s2O, mv2s, s2s);
  fused<<<1024, 512, 0, stream>>>(mv1, mv2, sc1, sc2, refmv, bias, out);
}

// Round 7
// 141.438 us; speedup vs baseline: 1.2749x; 1.2749x over previous
//
#include <hip/hip_runtime.h>
#include <cstdint>

#define OUT_S_OFF 33554432ull   // 8*4096*64*16

typedef short s16x8 __attribute__((ext_vector_type(8)));
typedef float f32x4 __attribute__((ext_vector_type(4)));
typedef unsigned int u32x2 __attribute__((ext_vector_type(2)));

// ---------------- compile-time geometric algebra tables ----------------
constexpr int BM_[16]   = {0,1,2,4,8,3,5,9,6,10,12,7,11,13,14,15};
constexpr int IDXm_[16] = {0,1,2,5,3,6,8,11,4,7,9,12,10,13,14,15};
constexpr int G_[16]    = {0,1,1,1,1,2,2,2,2,2,2,3,3,3,3,4};
constexpr int SRC_[16]  = {0,0,2,3,4,2,3,4,8,9,10,8,9,10,14,14};
constexpr int HASP_[16] = {0,1,0,0,0,1,1,1,0,0,0,1,1,1,0,1};
constexpr int A2_[16]   = {0,5,0,0,0,6,6,6,0,0,0,7,7,7,0,8};

constexpr int pcnt_(int x){ int c=0; for(int b=0;b<8;b++) c += (x>>b)&1; return c; }
constexpr int par_(int A,int B){ int sw=0; for(int b=0;b<4;b++) if((B>>b)&1) sw += pcnt_(A>>(b+1)); return (sw&1)?-1:1; }
constexpr int sgnv_(int b){ return par_(BM_[b], 15 & ~BM_[b]); }

struct GTab { int cnt[16]; signed char jj[16][16]; signed char kk[16][16]; signed char ss[16][16]; };

constexpr GTab mk_cayley(){
  GTab t{};
  for(int j=0;j<16;j++) for(int k=0;k<16;k++){
    int A=BM_[j], B=BM_[k];
    if(A & B & 1) continue;
    int i = IDXm_[A^B]; int s = par_(A,B);
    int n = t.cnt[i]; t.jj[i][n]=(signed char)j; t.kk[i][n]=(signed char)k; t.ss[i][n]=(signed char)s; t.cnt[i]=n+1;
  }
  return t;
}
constexpr GTab mk_join(){
  GTab t{};
  for(int j=0;j<16;j++) for(int k=0;k<16;k++){
    int cj = 15 & ~BM_[j], ck = 15 & ~BM_[k];
    if(cj & ck) continue;
    int m  = cj | ck;
    int w  = par_(cj, ck);
    int mp = IDXm_[15 & ~m];
    int s  = sgnv_(j)*sgnv_(k)*w*sgnv_(mp);
    int n = t.cnt[mp]; t.jj[mp][n]=(signed char)j; t.kk[mp][n]=(signed char)k; t.ss[mp][n]=(signed char)s; t.cnt[mp]=n+1;
  }
  return t;
}

__device__ __forceinline__ unsigned short f2bf(float f){
  unsigned u = __float_as_uint(f);
  return (unsigned short)((u + 0x7fffu + ((u>>16)&1u)) >> 16);
}
__device__ __forceinline__ unsigned int pack2(float a, float b){
  return (unsigned int)f2bf(a) | ((unsigned int)f2bf(b) << 16);
}

// ---------------- slab-indexed prepacked weights (B-operand fragments) ----------------
// frag element (lane,j): local-y = lane&15 ; k-in-32 = ((lane>>4)&3)*8 + j
__device__ unsigned short g_WinSlab [4*9*2*2*512]; // [m][d 0..8][s 0..1][h]  (147KB)
__device__ unsigned short g_WinS2   [4*2*2*512];   // [m][s][h]               (16KB)
__device__ unsigned short g_WoutSlab[9*2*4*512];   // [d][s][nt]              (72KB)
__device__ unsigned short g_WoutS2  [4*4*512];     // [ss][nt]                (16KB)
__device__ unsigned short g_WsB     [6*4*512];     // [s 0..5][nt]            (24KB)

__global__ __launch_bounds__(256) void prepack(
    const float* wL, const float* wR, const float* wJL, const float* wJR, const float* wO,
    const float* s2L, const float* s2R, const float* s2JL, const float* s2JR,
    const float* s2O, const float* mv2s, const float* s2s)
{
  int idx = blockIdx.x*256 + threadIdx.x;
  if (idx < 73728) {                         // g_WinSlab
    int j=idx&7, l=(idx>>3)&63, h=(idx>>9)&1, s=(idx>>10)&1;
    int md=idx>>11; int d=md%9, m=md/9;
    int y=h*16+(l&15), k=s*32+((l>>4)&3)*8+j;
    const float* w = (m==0)?wL:(m==1)?wR:(m==2)?wJL:wJR;
    g_WinSlab[idx] = f2bf(w[(y*64+k)*9 + d]);
  } else if (idx < 81920) {                  // g_WinS2
    int t2=idx-73728;
    int j=t2&7, l=(t2>>3)&63, h=(t2>>9)&1, s=(t2>>10)&1, m=t2>>11;
    int y=h*16+(l&15), k=s*32+((l>>4)&3)*8+j;
    const float* s2 = (m==0)?s2L:(m==1)?s2R:(m==2)?s2JL:s2JR;
    g_WinS2[t2] = f2bf(s2[y*64+k]);
  } else if (idx < 118784) {                 // g_WoutSlab
    int t3=idx-81920;
    int j=t3&7, l=(t3>>3)&63, nt=(t3>>9)&3, s=(t3>>11)&1, d=t3>>12;
    int y=nt*16+(l&15), k=s*32+((l>>4)&3)*8+j;
    g_WoutSlab[t3] = f2bf(wO[(y*64+k)*9 + d]);
  } else if (idx < 126976) {                 // g_WoutS2
    int t4=idx-118784;
    int j=t4&7, l=(t4>>3)&63, nt=(t4>>9)&3, ss=t4>>11;
    int y=nt*16+(l&15), kk=((l>>4)&3)*8+j;
    g_WoutS2[t4] = f2bf(s2O[y*128 + ss*32 + kk]);
  } else if (idx < 139264) {                 // g_WsB
    int t5=idx-126976;
    int j=t5&7, l=(t5>>3)&63, nt=(t5>>9)&3, s=t5>>11;
    int y=nt*16+(l&15), kk=((l>>4)&3)*8+j;
    float v = (s<2) ? mv2s[y*64 + s*32 + kk] : s2s[y*128 + (s-2)*32 + kk];
    g_WsB[t5] = f2bf(v);
  }
}

// ---------------- fused main kernel ----------------
// 256 threads = 4 waves, 16 tokens/block; mv1 in LDS, mv2 prefetched to
// registers (packed bf16) during P1a, then written into the same buffer.
// P1/P2 roles: (g = wv>>1 : 0=gp(L,R), 1=join(JL,JR)) x (h = wv&1)
// P3 roles: nt = wv
__global__ __launch_bounds__(256, 3) void fused(
    const float* __restrict__ mv1, const float* __restrict__ mv2,
    const float* __restrict__ sc1, const float* __restrict__ sc2,
    const float* __restrict__ refmv, const float* __restrict__ bias,
    float* __restrict__ out)
{
  __shared__ unsigned int s_mv[8192];   // [(i*16+t)*32 + dw], 32KB; mv1 -> mv2 -> hidden
  __shared__ unsigned int s_sc[1024];   // [t*64 + dw], 4KB (s_cat bf16, swizzled)
  __shared__ float s_ref[16];

  const int tid  = threadIdx.x;
  const int lane = tid & 63, wv = tid >> 6;
  const int tr   = lane & 15, u = lane >> 4;
  const int g    = wv >> 1,  h = wv & 1;
  const size_t tok0 = (size_t)blockIdx.x * 16;

  auto stage_load = [&](const float* __restrict__ src, int it, float4* Fr){
    int flat = tid + it*256;
    int x2 = flat & 31, t = flat >> 5;
    const float* b0 = src + (tok0+t)*1024 + x2*32;
    #pragma unroll
    for (int q=0;q<4;q++){
      Fr[q]   = *(const float4*)(b0 + q*4);
      Fr[4+q] = *(const float4*)(b0 + 16 + q*4);
    }
  };
  auto stage_write = [&](int it, const float4* Fr){
    int flat = tid + it*256;
    int x2 = flat & 31, t = flat >> 5;
    unsigned int* dst = &s_mv[t*32 + (x2 ^ ((t&7)<<2))];
    #pragma unroll
    for (int q=0;q<4;q++){
      #pragma unroll
      for (int e=0;e<4;e++){
        int i = q*4 + e;
        dst[i*512] = pack2(((const float*)&Fr[q])[e], ((const float*)&Fr[4+q])[e]);
      }
    }
  };
  auto stage_write_pk = [&](const unsigned int* PF){
    #pragma unroll
    for (int it=0; it<2; ++it){
      int flat = tid + it*256;
      int x2 = flat & 31, t = flat >> 5;
      unsigned int* dst = &s_mv[t*32 + (x2 ^ ((t&7)<<2))];
      #pragma unroll
      for (int i=0;i<16;i++) dst[i*512] = PF[it*16 + i];
    }
  };

  auto afrag = [&](int comp, int sh)->s16x8 {
    const unsigned short* p = (const unsigned short*)s_mv;
    return *(const s16x8*)&p[(comp*16 + tr)*64 + (((sh*4 + u) ^ (tr&7)) << 3)];
  };
  auto scfrag = [&](int ss)->s16x8 {
    const unsigned short* p = (const unsigned short*)s_sc;
    return *(const s16x8*)&p[tr*128 + (((ss*4 + u) ^ (tr&7)) << 3)];
  };
  auto slabIn = [&](int m,int d,int s)->s16x8 {
    return *(const s16x8*)&g_WinSlab[((((m*9+d)*2+s)*2+h)*512) + lane*8];
  };
  auto s2In = [&](int m,int s)->s16x8 {
    return *(const s16x8*)&g_WinS2[(((m*2+s)*2+h)*512) + lane*8];
  };
  auto slabOut = [&](int d,int s,int nt)->s16x8 {
    return *(const s16x8*)&g_WoutSlab[(((d*2+s)*4+nt)*512) + lane*8];
  };
  auto s2Out = [&](int ss,int nt)->s16x8 {
    return *(const s16x8*)&g_WoutS2[((ss*4+nt)*512) + lane*8];
  };
  auto bfragS = [&](int s,int nt)->s16x8 {
    return *(const s16x8*)&g_WsB[((s*4+nt)*512) + lane*8];
  };

  // ---- P0: stage mv1 + scalars + ref ----
  {
    float4 F0[8], F1[8];
    stage_load(mv1, 0, F0);
    stage_load(mv1, 1, F1);
    #pragma unroll
    for (int it=0; it<4; ++it){
      int flat = tid + it*256;
      int cp = flat & 63, t = flat >> 6;
      float a, b;
      if (cp < 32){ const float* p = sc1 + (tok0+t)*64 + cp*2;      a=p[0]; b=p[1]; }
      else        { const float* p = sc2 + (tok0+t)*64 + (cp-32)*2; a=p[0]; b=p[1]; }
      s_sc[t*64 + (cp ^ ((t&7)<<2))] = pack2(a,b);
    }
    if (tid < 16) s_ref[tid] = refmv[(tok0+tid)*16 + 15];
    stage_write(0, F0);
    stage_write(1, F1);
  }
  __syncthreads();

  // ---- prefetch mv2 tile into registers, packed bf16 (32 VGPRs) ----
  unsigned int PF[32];
  {
    float4 F[8];
    stage_load(mv2, 0, F);
    #pragma unroll
    for (int q=0;q<4;q++)
      #pragma unroll
      for (int e=0;e<4;e++)
        PF[q*4+e] = pack2(((const float*)&F[q])[e], ((const float*)&F[4+q])[e]);
    stage_load(mv2, 1, F);
    #pragma unroll
    for (int q=0;q<4;q++)
      #pragma unroll
      for (int e=0;e<4;e++)
        PF[16+q*4+e] = pack2(((const float*)&F[q])[e], ((const float*)&F[4+q])[e]);
  }

  // ---- P1a: A-side maps from mv1 (gp: L ; join: JL); sc1 folded; pack acc ----
  u32x2 accAp[16], accBp[16];
  const int mA = (g==0) ? 0 : 2;
  const int mB = (g==0) ? 1 : 3;
  #pragma unroll
  for (int i=0;i<16;i++){
    f32x4 a = (f32x4)0.f;
    a = __builtin_amdgcn_mfma_f32_16x16x32_bf16(afrag(i,0), slabIn(mA,G_[i],0), a,0,0,0);
    a = __builtin_amdgcn_mfma_f32_16x16x32_bf16(afrag(i,1), slabIn(mA,G_[i],1), a,0,0,0);
    if (HASP_[i]){
      a = __builtin_amdgcn_mfma_f32_16x16x32_bf16(afrag(SRC_[i],0), slabIn(mA,A2_[i],0), a,0,0,0);
      a = __builtin_amdgcn_mfma_f32_16x16x32_bf16(afrag(SRC_[i],1), slabIn(mA,A2_[i],1), a,0,0,0);
    } else if (i==0){
      a = __builtin_amdgcn_mfma_f32_16x16x32_bf16(scfrag(0), s2In(mA,0), a,0,0,0);
      a = __builtin_amdgcn_mfma_f32_16x16x32_bf16(scfrag(1), s2In(mA,1), a,0,0,0);
    }
    accAp[i].x = pack2(a[0], a[1]);
    accAp[i].y = pack2(a[2], a[3]);
  }
  __syncthreads();   // all P1a reads of s_mv complete

  // ---- P0b: write prefetched mv2 tile into s_mv ----
  stage_write_pk(PF);
  __syncthreads();

  // ---- P1c: B-side maps from mv2 (gp: R ; join: JR); sc2 folded ----
  #pragma unroll
  for (int i=0;i<16;i++){
    f32x4 b = (f32x4)0.f;
    b = __builtin_amdgcn_mfma_f32_16x16x32_bf16(afrag(i,0), slabIn(mB,G_[i],0), b,0,0,0);
    b = __builtin_amdgcn_mfma_f32_16x16x32_bf16(afrag(i,1), slabIn(mB,G_[i],1), b,0,0,0);
    if (HASP_[i]){
      b = __builtin_amdgcn_mfma_f32_16x16x32_bf16(afrag(SRC_[i],0), slabIn(mB,A2_[i],0), b,0,0,0);
      b = __builtin_amdgcn_mfma_f32_16x16x32_bf16(afrag(SRC_[i],1), slabIn(mB,A2_[i],1), b,0,0,0);
    } else if (i==0){
      b = __builtin_amdgcn_mfma_f32_16x16x32_bf16(scfrag(2), s2In(mB,0), b,0,0,0);
      b = __builtin_amdgcn_mfma_f32_16x16x32_bf16(scfrag(3), s2In(mB,1), b,0,0,0);
    }
    accBp[i].x = pack2(b[0], b[1]);
    accBp[i].y = pack2(b[2], b[3]);
  }
  __syncthreads();   // all P1c reads done before hidden overwrite

  // ---- P2: Cayley GP / join from packed-bf16 regs; write hidden (aliases s_mv) ----
  {
    unsigned short* hidp = (unsigned short*)s_mv;
    if (g == 0){
      constexpr GTab CAY = mk_cayley();
      #pragma unroll
      for (int r=0;r<4;r++){
        const int t = u*4 + r;
        float L[16], R[16];
        #pragma unroll
        for (int j2=0;j2<16;j2++){
          unsigned wa = (r&2) ? accAp[j2].y : accAp[j2].x;
          unsigned wb = (r&2) ? accBp[j2].y : accBp[j2].x;
          L[j2] = __uint_as_float((r&1) ? (wa & 0xffff0000u) : (wa << 16));
          R[j2] = __uint_as_float((r&1) ? (wb & 0xffff0000u) : (wb << 16));
        }
        const int c = h*16 + tr;
        #pragma unroll
        for (int i=0;i<16;i++){
          float a = 0.f;
          #pragma unroll
          for (int e=0;e<CAY.cnt[i];e++){
            float p = L[(int)CAY.jj[i][e]] * R[(int)CAY.kk[i][e]];
            a = (CAY.ss[i][e] > 0) ? (a + p) : (a - p);
          }
          hidp[(i*16 + t)*64 + (c ^ ((t&7)<<3))] = f2bf(a);
        }
      }
    } else {
      constexpr GTab JNT = mk_join();
      #pragma unroll
      for (int r=0;r<4;r++){
        const int t = u*4 + r;
        float rv = s_ref[t];
        float L[16], R[16];
        #pragma unroll
        for (int j2=0;j2<16;j2++){
          unsigned wa = (r&2) ? accAp[j2].y : accAp[j2].x;
          unsigned wb = (r&2) ? accBp[j2].y : accBp[j2].x;
          L[j2] = __uint_as_float((r&1) ? (wa & 0xffff0000u) : (wa << 16));
          R[j2] = __uint_as_float((r&1) ? (wb & 0xffff0000u) : (wb << 16));
        }
        const int c = 32 + h*16 + tr;
        #pragma unroll
        for (int i=0;i<16;i++){
          float a = 0.f;
          #pragma unroll
          for (int e=0;e<JNT.cnt[i];e++){
            float p = L[(int)JNT.jj[i][e]] * R[(int)JNT.kk[i][e]];
            a = (JNT.ss[i][e] > 0) ? (a + p) : (a - p);
          }
          hidp[(i*16 + t)*64 + (c ^ ((t&7)<<3))] = f2bf(a * rv);
        }
      }
    }
  }
  __syncthreads();

  // ---- P3: output equi-linear + scalar head via MFMA; wave = n-tile ----
  {
    const int nt = wv;
    f32x4 accO[16]; f32x4 accS = (f32x4)0.f;
    #pragma unroll
    for (int i=0;i<16;i++) accO[i] = (f32x4)0.f;

    s16x8 h00 = afrag(0,0), h01 = afrag(0,1);

    #pragma unroll
    for (int i=0;i<16;i++){
      s16x8 a0 = (i==0) ? h00 : afrag(i,0);
      s16x8 a1 = (i==0) ? h01 : afrag(i,1);
      accO[i] = __builtin_amdgcn_mfma_f32_16x16x32_bf16(a0, slabOut(G_[i],0,nt), accO[i],0,0,0);
      accO[i] = __builtin_amdgcn_mfma_f32_16x16x32_bf16(a1, slabOut(G_[i],1,nt), accO[i],0,0,0);
      if (HASP_[i]){
        accO[i] = __builtin_amdgcn_mfma_f32_16x16x32_bf16(afrag(SRC_[i],0), slabOut(A2_[i],0,nt), accO[i],0,0,0);
        accO[i] = __builtin_amdgcn_mfma_f32_16x16x32_bf16(afrag(SRC_[i],1), slabOut(A2_[i],1,nt), accO[i],0,0,0);
      } else if (i==0){
        #pragma unroll
        for (int ss=0;ss<4;ss++)
          accO[0] = __builtin_amdgcn_mfma_f32_16x16x32_bf16(scfrag(ss), s2Out(ss,nt), accO[0],0,0,0);
      }
    }
    accS = __builtin_amdgcn_mfma_f32_16x16x32_bf16(h00, bfragS(0,nt), accS,0,0,0);
    accS = __builtin_amdgcn_mfma_f32_16x16x32_bf16(h01, bfragS(1,nt), accS,0,0,0);
    #pragma unroll
    for (int ss=0;ss<4;ss++)
      accS = __builtin_amdgcn_mfma_f32_16x16x32_bf16(scfrag(ss), bfragS(2+ss,nt), accS,0,0,0);

    const int y = nt*16 + tr;
    const float bv = bias[y];
    #pragma unroll
    for (int r=0;r<4;r++){
      const int t = u*4 + r;
      out[OUT_S_OFF + (tok0+t)*64 + y] = accS[r] + bv;
      float* ob = out + (tok0+t)*1024 + y*16;
      #pragma unroll
      for (int iq=0;iq<4;iq++){
        f32x4 v = { accO[iq*4+0][r], accO[iq*4+1][r], accO[iq*4+2][r], accO[iq*4+3][r] };
        *(f32x4*)(ob + iq*4) = v;
      }
    }
  }
}

extern "C" void kernel_launch(void* const* d_in, const int* in_sizes, int n_in,
                              void* d_out, int out_size, void* d_ws, size_t ws_size,
                              hipStream_t stream) {
  const float* mv1   = (const float*)d_in[0];
  const float* mv2   = (const float*)d_in[1];
  const float* sc1   = (const float*)d_in[2];
  const float* sc2   = (const float*)d_in[3];
  const float* refmv = (const float*)d_in[4];
  const float* wL    = (const float*)d_in[5];
  const float* s2L   = (const float*)d_in[6];
  const float* wR    = (const float*)d_in[7];
  const float* s2R   = (const float*)d_in[8];
  const float* wJL   = (const float*)d_in[9];
  const float* s2JL  = (const float*)d_in[10];
  const float* wJR   = (const float*)d_in[11];
  const float* s2JR  = (const float*)d_in[12];
  const float* wO    = (const float*)d_in[13];
  const float* s2O   = (const float*)d_in[14];
  const float* mv2s  = (const float*)d_in[15];
  const float* s2s   = (const float*)d_in[16];
  const float* bias  = (const float*)d_in[17];
  float* out = (float*)d_out;

  prepack<<<544, 256, 0, stream>>>(wL,wR,wJL,wJR,wO, s2L,s2R,s2JL,s2JR, s2O, mv2s, s2s);
  fused<<<2048, 256, 0, stream>>>(mv1, mv2, sc1, sc2, refmv, bias, out);
}

// Round 8
// 133.703 us; speedup vs baseline: 1.3486x; 1.0579x over previous
//
#include <hip/hip_runtime.h>
#include <cstdint>

#define OUT_S_OFF 33554432ull   // 8*4096*64*16

typedef short s16x8 __attribute__((ext_vector_type(8)));
typedef float f32x4 __attribute__((ext_vector_type(4)));
typedef unsigned int u32x2 __attribute__((ext_vector_type(2)));

// ---------------- compile-time geometric algebra tables ----------------
constexpr int BM_[16]   = {0,1,2,4,8,3,5,9,6,10,12,7,11,13,14,15};
constexpr int IDXm_[16] = {0,1,2,5,3,6,8,11,4,7,9,12,10,13,14,15};
constexpr int G_[16]    = {0,1,1,1,1,2,2,2,2,2,2,3,3,3,3,4};
constexpr int SRC_[16]  = {0,0,2,3,4,2,3,4,8,9,10,8,9,10,14,14};
constexpr int HASP_[16] = {0,1,0,0,0,1,1,1,0,0,0,1,1,1,0,1};
constexpr int A2_[16]   = {0,5,0,0,0,6,6,6,0,0,0,7,7,7,0,8};

constexpr int pcnt_(int x){ int c=0; for(int b=0;b<8;b++) c += (x>>b)&1; return c; }
constexpr int par_(int A,int B){ int sw=0; for(int b=0;b<4;b++) if((B>>b)&1) sw += pcnt_(A>>(b+1)); return (sw&1)?-1:1; }
constexpr int sgnv_(int b){ return par_(BM_[b], 15 & ~BM_[b]); }

struct GTab { int cnt[16]; signed char jj[16][16]; signed char kk[16][16]; signed char ss[16][16]; };

constexpr GTab mk_cayley(){
  GTab t{};
  for(int j=0;j<16;j++) for(int k=0;k<16;k++){
    int A=BM_[j], B=BM_[k];
    if(A & B & 1) continue;
    int i = IDXm_[A^B]; int s = par_(A,B);
    int n = t.cnt[i]; t.jj[i][n]=(signed char)j; t.kk[i][n]=(signed char)k; t.ss[i][n]=(signed char)s; t.cnt[i]=n+1;
  }
  return t;
}
constexpr GTab mk_join(){
  GTab t{};
  for(int j=0;j<16;j++) for(int k=0;k<16;k++){
    int cj = 15 & ~BM_[j], ck = 15 & ~BM_[k];
    if(cj & ck) continue;
    int m  = cj | ck;
    int w  = par_(cj, ck);
    int mp = IDXm_[15 & ~m];
    int s  = sgnv_(j)*sgnv_(k)*w*sgnv_(mp);
    int n = t.cnt[mp]; t.jj[mp][n]=(signed char)j; t.kk[mp][n]=(signed char)k; t.ss[mp][n]=(signed char)s; t.cnt[mp]=n+1;
  }
  return t;
}

__device__ __forceinline__ unsigned short f2bf(float f){
  unsigned u = __float_as_uint(f);
  return (unsigned short)((u + 0x7fffu + ((u>>16)&1u)) >> 16);
}
__device__ __forceinline__ unsigned int pack2(float a, float b){
  return (unsigned int)f2bf(a) | ((unsigned int)f2bf(b) << 16);
}

// ---------------- slab-indexed prepacked weights (B-operand fragments) ----------------
// frag element (lane,j): local-y = lane&15 ; k-in-32 = ((lane>>4)&3)*8 + j
__device__ unsigned short g_WinSlab [4*9*2*2*512]; // [m][d 0..8][s 0..1][h]  (147KB)
__device__ unsigned short g_WinS2   [4*2*2*512];   // [m][s][h]               (16KB)
__device__ unsigned short g_WoutSlab[9*2*4*512];   // [d][s][nt]              (72KB)
__device__ unsigned short g_WoutS2  [4*4*512];     // [ss][nt]                (16KB)
__device__ unsigned short g_WsB     [6*4*512];     // [s 0..5][nt]            (24KB)

__global__ __launch_bounds__(256) void prepack(
    const float* wL, const float* wR, const float* wJL, const float* wJR, const float* wO,
    const float* s2L, const float* s2R, const float* s2JL, const float* s2JR,
    const float* s2O, const float* mv2s, const float* s2s)
{
  int idx = blockIdx.x*256 + threadIdx.x;
  if (idx < 73728) {                         // g_WinSlab
    int j=idx&7, l=(idx>>3)&63, h=(idx>>9)&1, s=(idx>>10)&1;
    int md=idx>>11; int d=md%9, m=md/9;
    int y=h*16+(l&15), k=s*32+((l>>4)&3)*8+j;
    const float* w = (m==0)?wL:(m==1)?wR:(m==2)?wJL:wJR;
    g_WinSlab[idx] = f2bf(w[(y*64+k)*9 + d]);
  } else if (idx < 81920) {                  // g_WinS2
    int t2=idx-73728;
    int j=t2&7, l=(t2>>3)&63, h=(t2>>9)&1, s=(t2>>10)&1, m=t2>>11;
    int y=h*16+(l&15), k=s*32+((l>>4)&3)*8+j;
    const float* s2 = (m==0)?s2L:(m==1)?s2R:(m==2)?s2JL:s2JR;
    g_WinS2[t2] = f2bf(s2[y*64+k]);
  } else if (idx < 118784) {                 // g_WoutSlab
    int t3=idx-81920;
    int j=t3&7, l=(t3>>3)&63, nt=(t3>>9)&3, s=(t3>>11)&1, d=t3>>12;
    int y=nt*16+(l&15), k=s*32+((l>>4)&3)*8+j;
    g_WoutSlab[t3] = f2bf(wO[(y*64+k)*9 + d]);
  } else if (idx < 126976) {                 // g_WoutS2
    int t4=idx-118784;
    int j=t4&7, l=(t4>>3)&63, nt=(t4>>9)&3, ss=t4>>11;
    int y=nt*16+(l&15), kk=((l>>4)&3)*8+j;
    g_WoutS2[t4] = f2bf(s2O[y*128 + ss*32 + kk]);
  } else if (idx < 139264) {                 // g_WsB
    int t5=idx-126976;
    int j=t5&7, l=(t5>>3)&63, nt=(t5>>9)&3, s=t5>>11;
    int y=nt*16+(l&15), kk=((l>>4)&3)*8+j;
    float v = (s<2) ? mv2s[y*64 + s*32 + kk] : s2s[y*128 + (s-2)*32 + kk];
    g_WsB[t5] = f2bf(v);
  }
}

// ---------------- fused main kernel ----------------
// 256 threads = 4 waves, 16 tokens/block; mv1 in LDS, mv2 prefetched to
// registers (packed bf16, issued BEFORE the first barrier), then written
// into the same LDS buffer after P1a.
// P1/P2 roles: (g = wv>>1 : 0=gp(L,R), 1=join(JL,JR)) x (h = wv&1)
// P3 roles: nt = wv
// NOTE: launch_bounds min-waves MUST stay at 2 — (256,3)/(512,4) made the
// allocator spill (R4/R6/R7: +50..160MB scratch traffic, net regression).
__global__ __launch_bounds__(256, 2) void fused(
    const float* __restrict__ mv1, const float* __restrict__ mv2,
    const float* __restrict__ sc1, const float* __restrict__ sc2,
    const float* __restrict__ refmv, const float* __restrict__ bias,
    float* __restrict__ out)
{
  __shared__ unsigned int s_mv[8192];   // [(i*16+t)*32 + dw], 32KB; mv1 -> mv2 -> hidden
  __shared__ unsigned int s_sc[1024];   // [t*64 + dw], 4KB (s_cat bf16, swizzled)
  __shared__ float s_ref[16];

  const int tid  = threadIdx.x;
  const int lane = tid & 63, wv = tid >> 6;
  const int tr   = lane & 15, u = lane >> 4;
  const int g    = wv >> 1,  h = wv & 1;
  const size_t tok0 = (size_t)blockIdx.x * 16;

  auto stage_load = [&](const float* __restrict__ src, int it, float4* Fr){
    int flat = tid + it*256;
    int x2 = flat & 31, t = flat >> 5;
    const float* b0 = src + (tok0+t)*1024 + x2*32;
    #pragma unroll
    for (int q=0;q<4;q++){
      Fr[q]   = *(const float4*)(b0 + q*4);
      Fr[4+q] = *(const float4*)(b0 + 16 + q*4);
    }
  };
  auto stage_write = [&](int it, const float4* Fr){
    int flat = tid + it*256;
    int x2 = flat & 31, t = flat >> 5;
    unsigned int* dst = &s_mv[t*32 + (x2 ^ ((t&7)<<2))];
    #pragma unroll
    for (int q=0;q<4;q++){
      #pragma unroll
      for (int e=0;e<4;e++){
        int i = q*4 + e;
        dst[i*512] = pack2(((const float*)&Fr[q])[e], ((const float*)&Fr[4+q])[e]);
      }
    }
  };
  auto stage_write_pk = [&](const unsigned int* PF){
    #pragma unroll
    for (int it=0; it<2; ++it){
      int flat = tid + it*256;
      int x2 = flat & 31, t = flat >> 5;
      unsigned int* dst = &s_mv[t*32 + (x2 ^ ((t&7)<<2))];
      #pragma unroll
      for (int i=0;i<16;i++) dst[i*512] = PF[it*16 + i];
    }
  };

  auto afrag = [&](int comp, int sh)->s16x8 {
    const unsigned short* p = (const unsigned short*)s_mv;
    return *(const s16x8*)&p[(comp*16 + tr)*64 + (((sh*4 + u) ^ (tr&7)) << 3)];
  };
  auto scfrag = [&](int ss)->s16x8 {
    const unsigned short* p = (const unsigned short*)s_sc;
    return *(const s16x8*)&p[tr*128 + (((ss*4 + u) ^ (tr&7)) << 3)];
  };
  auto slabIn = [&](int m,int d,int s)->s16x8 {
    return *(const s16x8*)&g_WinSlab[((((m*9+d)*2+s)*2+h)*512) + lane*8];
  };
  auto s2In = [&](int m,int s)->s16x8 {
    return *(const s16x8*)&g_WinS2[(((m*2+s)*2+h)*512) + lane*8];
  };
  auto slabOut = [&](int d,int s,int nt)->s16x8 {
    return *(const s16x8*)&g_WoutSlab[(((d*2+s)*4+nt)*512) + lane*8];
  };
  auto s2Out = [&](int ss,int nt)->s16x8 {
    return *(const s16x8*)&g_WoutS2[((ss*4+nt)*512) + lane*8];
  };
  auto bfragS = [&](int s,int nt)->s16x8 {
    return *(const s16x8*)&g_WsB[((s*4+nt)*512) + lane*8];
  };

  // ---- P0: stage mv1 + scalars + ref; prefetch mv2 to regs BEFORE barrier ----
  unsigned int PF[32];
  {
    float4 F0[8], F1[8];
    stage_load(mv1, 0, F0);
    stage_load(mv1, 1, F1);
    #pragma unroll
    for (int it=0; it<4; ++it){
      int flat = tid + it*256;
      int cp = flat & 63, t = flat >> 6;
      float a, b;
      if (cp < 32){ const float* p = sc1 + (tok0+t)*64 + cp*2;      a=p[0]; b=p[1]; }
      else        { const float* p = sc2 + (tok0+t)*64 + (cp-32)*2; a=p[0]; b=p[1]; }
      s_sc[t*64 + (cp ^ ((t&7)<<2))] = pack2(a,b);
    }
    if (tid < 16) s_ref[tid] = refmv[(tok0+tid)*16 + 15];
    stage_write(0, F0);
    stage_write(1, F1);
    // mv2 prefetch: global loads are LDS-independent; overlap barrier + P1a
    float4 F[8];
    stage_load(mv2, 0, F);
    #pragma unroll
    for (int q=0;q<4;q++)
      #pragma unroll
      for (int e=0;e<4;e++)
        PF[q*4+e] = pack2(((const float*)&F[q])[e], ((const float*)&F[4+q])[e]);
    stage_load(mv2, 1, F);
    #pragma unroll
    for (int q=0;q<4;q++)
      #pragma unroll
      for (int e=0;e<4;e++)
        PF[16+q*4+e] = pack2(((const float*)&F[q])[e], ((const float*)&F[4+q])[e]);
  }
  __syncthreads();

  // ---- P1a: A-side maps from mv1 (gp: L ; join: JL); sc1 folded; pack acc ----
  u32x2 accAp[16], accBp[16];
  const int mA = (g==0) ? 0 : 2;
  const int mB = (g==0) ? 1 : 3;
  #pragma unroll
  for (int i=0;i<16;i++){
    f32x4 a = (f32x4)0.f;
    a = __builtin_amdgcn_mfma_f32_16x16x32_bf16(afrag(i,0), slabIn(mA,G_[i],0), a,0,0,0);
    a = __builtin_amdgcn_mfma_f32_16x16x32_bf16(afrag(i,1), slabIn(mA,G_[i],1), a,0,0,0);
    if (HASP_[i]){
      a = __builtin_amdgcn_mfma_f32_16x16x32_bf16(afrag(SRC_[i],0), slabIn(mA,A2_[i],0), a,0,0,0);
      a = __builtin_amdgcn_mfma_f32_16x16x32_bf16(afrag(SRC_[i],1), slabIn(mA,A2_[i],1), a,0,0,0);
    } else if (i==0){
      a = __builtin_amdgcn_mfma_f32_16x16x32_bf16(scfrag(0), s2In(mA,0), a,0,0,0);
      a = __builtin_amdgcn_mfma_f32_16x16x32_bf16(scfrag(1), s2In(mA,1), a,0,0,0);
    }
    accAp[i].x = pack2(a[0], a[1]);
    accAp[i].y = pack2(a[2], a[3]);
  }
  __syncthreads();   // all P1a reads of s_mv complete

  // ---- P0b: write prefetched mv2 tile into s_mv ----
  stage_write_pk(PF);
  __syncthreads();

  // ---- P1c: B-side maps from mv2 (gp: R ; join: JR); sc2 folded ----
  #pragma unroll
  for (int i=0;i<16;i++){
    f32x4 b = (f32x4)0.f;
    b = __builtin_amdgcn_mfma_f32_16x16x32_bf16(afrag(i,0), slabIn(mB,G_[i],0), b,0,0,0);
    b = __builtin_amdgcn_mfma_f32_16x16x32_bf16(afrag(i,1), slabIn(mB,G_[i],1), b,0,0,0);
    if (HASP_[i]){
      b = __builtin_amdgcn_mfma_f32_16x16x32_bf16(afrag(SRC_[i],0), slabIn(mB,A2_[i],0), b,0,0,0);
      b = __builtin_amdgcn_mfma_f32_16x16x32_bf16(afrag(SRC_[i],1), slabIn(mB,A2_[i],1), b,0,0,0);
    } else if (i==0){
      b = __builtin_amdgcn_mfma_f32_16x16x32_bf16(scfrag(2), s2In(mB,0), b,0,0,0);
      b = __builtin_amdgcn_mfma_f32_16x16x32_bf16(scfrag(3), s2In(mB,1), b,0,0,0);
    }
    accBp[i].x = pack2(b[0], b[1]);
    accBp[i].y = pack2(b[2], b[3]);
  }
  __syncthreads();   // all P1c reads done before hidden overwrite

  // ---- P2: Cayley GP / join from packed-bf16 regs; write hidden (aliases s_mv) ----
  {
    unsigned short* hidp = (unsigned short*)s_mv;
    if (g == 0){
      constexpr GTab CAY = mk_cayley();
      #pragma unroll
      for (int r=0;r<4;r++){
        const int t = u*4 + r;
        float L[16], R[16];
        #pragma unroll
        for (int j2=0;j2<16;j2++){
          unsigned wa = (r&2) ? accAp[j2].y : accAp[j2].x;
          unsigned wb = (r&2) ? accBp[j2].y : accBp[j2].x;
          L[j2] = __uint_as_float((r&1) ? (wa & 0xffff0000u) : (wa << 16));
          R[j2] = __uint_as_float((r&1) ? (wb & 0xffff0000u) : (wb << 16));
        }
        const int c = h*16 + tr;
        #pragma unroll
        for (int i=0;i<16;i++){
          float a = 0.f;
          #pragma unroll
          for (int e=0;e<CAY.cnt[i];e++){
            float p = L[(int)CAY.jj[i][e]] * R[(int)CAY.kk[i][e]];
            a = (CAY.ss[i][e] > 0) ? (a + p) : (a - p);
          }
          hidp[(i*16 + t)*64 + (c ^ ((t&7)<<3))] = f2bf(a);
        }
      }
    } else {
      constexpr GTab JNT = mk_join();
      #pragma unroll
      for (int r=0;r<4;r++){
        const int t = u*4 + r;
        float rv = s_ref[t];
        float L[16], R[16];
        #pragma unroll
        for (int j2=0;j2<16;j2++){
          unsigned wa = (r&2) ? accAp[j2].y : accAp[j2].x;
          unsigned wb = (r&2) ? accBp[j2].y : accBp[j2].x;
          L[j2] = __uint_as_float((r&1) ? (wa & 0xffff0000u) : (wa << 16));
          R[j2] = __uint_as_float((r&1) ? (wb & 0xffff0000u) : (wb << 16));
        }
        const int c = 32 + h*16 + tr;
        #pragma unroll
        for (int i=0;i<16;i++){
          float a = 0.f;
          #pragma unroll
          for (int e=0;e<JNT.cnt[i];e++){
            float p = L[(int)JNT.jj[i][e]] * R[(int)JNT.kk[i][e]];
            a = (JNT.ss[i][e] > 0) ? (a + p) : (a - p);
          }
          hidp[(i*16 + t)*64 + (c ^ ((t&7)<<3))] = f2bf(a * rv);
        }
      }
    }
  }
  __syncthreads();

  // ---- P3: output equi-linear + scalar head via MFMA; wave = n-tile ----
  {
    const int nt = wv;
    f32x4 accO[16]; f32x4 accS = (f32x4)0.f;
    #pragma unroll
    for (int i=0;i<16;i++) accO[i] = (f32x4)0.f;

    s16x8 h00 = afrag(0,0), h01 = afrag(0,1);

    #pragma unroll
    for (int i=0;i<16;i++){
      s16x8 a0 = (i==0) ? h00 : afrag(i,0);
      s16x8 a1 = (i==0) ? h01 : afrag(i,1);
      accO[i] = __builtin_amdgcn_mfma_f32_16x16x32_bf16(a0, slabOut(G_[i],0,nt), accO[i],0,0,0);
      accO[i] = __builtin_amdgcn_mfma_f32_16x16x32_bf16(a1, slabOut(G_[i],1,nt), accO[i],0,0,0);
      if (HASP_[i]){
        accO[i] = __builtin_amdgcn_mfma_f32_16x16x32_bf16(afrag(SRC_[i],0), slabOut(A2_[i],0,nt), accO[i],0,0,0);
        accO[i] = __builtin_amdgcn_mfma_f32_16x16x32_bf16(afrag(SRC_[i],1), slabOut(A2_[i],1,nt), accO[i],0,0,0);
      } else if (i==0){
        #pragma unroll
        for (int ss=0;ss<4;ss++)
          accO[0] = __builtin_amdgcn_mfma_f32_16x16x32_bf16(scfrag(ss), s2Out(ss,nt), accO[0],0,0,0);
      }
    }
    accS = __builtin_amdgcn_mfma_f32_16x16x32_bf16(h00, bfragS(0,nt), accS,0,0,0);
    accS = __builtin_amdgcn_mfma_f32_16x16x32_bf16(h01, bfragS(1,nt), accS,0,0,0);
    #pragma unroll
    for (int ss=0;ss<4;ss++)
      accS = __builtin_amdgcn_mfma_f32_16x16x32_bf16(scfrag(ss), bfragS(2+ss,nt), accS,0,0,0);

    const int y = nt*16 + tr;
    const float bv = bias[y];
    #pragma unroll
    for (int r=0;r<4;r++){
      const int t = u*4 + r;
      out[OUT_S_OFF + (tok0+t)*64 + y] = accS[r] + bv;
      float* ob = out + (tok0+t)*1024 + y*16;
      #pragma unroll
      for (int iq=0;iq<4;iq++){
        f32x4 v = { accO[iq*4+0][r], accO[iq*4+1][r], accO[iq*4+2][r], accO[iq*4+3][r] };
        *(f32x4*)(ob + iq*4) = v;
      }
    }
  }
}

extern "C" void kernel_launch(void* const* d_in, const int* in_sizes, int n_in,
                              void* d_out, int out_size, void* d_ws, size_t ws_size,
                              hipStream_t stream) {
  const float* mv1   = (const float*)d_in[0];
  const float* mv2   = (const float*)d_in[1];
  const float* sc1   = (const float*)d_in[2];
  const float* sc2   = (const float*)d_in[3];
  const float* refmv = (const float*)d_in[4];
  const float* wL    = (const float*)d_in[5];
  const float* s2L   = (const float*)d_in[6];
  const float* wR    = (const float*)d_in[7];
  const float* s2R   = (const float*)d_in[8];
  const float* wJL   = (const float*)d_in[9];
  const float* s2JL  = (const float*)d_in[10];
  const float* wJR   = (const float*)d_in[11];
  const float* s2JR  = (const float*)d_in[12];
  const float* wO    = (const float*)d_in[13];
  const float* s2O   = (const float*)d_in[14];
  const float* mv2s  = (const float*)d_in[15];
  const float* s2s   = (const float*)d_in[16];
  const float* bias  = (const float*)d_in[17];
  float* out = (float*)d_out;

  prepack<<<544, 256, 0, stream>>>(wL,wR,wJL,wJR,wO, s2L,s2R,s2JL,s2JR, s2O, mv2s, s2s);
  fused<<<2048, 256, 0, stream>>>(mv1, mv2, sc1, sc2, refmv, bias, out);
}